// Round 1
// baseline (10107.420 us; speedup 1.0000x reference)
//
#include <hip/hip_runtime.h>
#include <hip/hip_bf16.h>

// Problem constants
static constexpr int H_ = 1024;
static constexpr int W_ = 1024;
static constexpr int WIN_ = 32;
static constexpr int STR_ = 16;
static constexpr int NH_ = 63;          // (1024-32)/16 + 1
static constexpr int NPATCH_ = NH_ * NH_;  // 3969

// ---------------------------------------------------------------------------
// LDS layout (bytes), total 55264:
//   Region A [0, 30000):   sH1 bf16 [24][25][25]  (live conv1 -> end of o-loop)
//                          sWc f32  [64][24]      (live after o-loop) [0,6144)
//   Region B [30000, 38192): sP f32 [2][32][32]   (live load -> conv1)
//            [30000, 51168): sH2 f32 [12][441]    (live during o-loop)
//            [51168, 55264): sp  f32 [1024]       (p accumulator, zeroed early)
// ---------------------------------------------------------------------------
static constexpr int LDS_BYTES = 55264;

__global__ __launch_bounds__(640) void fused_patch_kernel(
    const float* __restrict__ x1, const float* __restrict__ x2,
    const float* __restrict__ c1b, const float* __restrict__ c2b,
    const float* __restrict__ d2b, const float* __restrict__ d1b,
    const float* __restrict__ lin_w, const float* __restrict__ lin_b,
    const float* __restrict__ w1t,   // [2*8*8][24]   (d,p,q) x o
    const float* __restrict__ w2t,   // [24*5*5][60]  (c,p,q) x o
    const float* __restrict__ dw2t,  // [60*5*5][24]  (o,dy,dx) x c
    const float* __restrict__ dw1,   // raw deconv1_w (24,1,2,8,8)
    float* __restrict__ recon)       // = d_out, accumulated with atomics
{
    __shared__ alignas(16) char sbuf[LDS_BYTES];
    __hip_bfloat16* sH1 = (__hip_bfloat16*)sbuf;       // 24*625 bf16
    float* sWc = (float*)sbuf;                          // 64*24 f32 (after o-loop)
    float* sP  = (float*)(sbuf + 30000);                // 2*1024 f32
    float* sH2 = (float*)(sbuf + 30000);                // 12*441 f32
    float* sp  = (float*)(sbuf + 51168);                // 1024 f32

    const int n  = blockIdx.x;
    const int pi = n / NH_, pj = n % NH_;
    const int t  = (int)threadIdx.x;
    const int Y0 = pi * STR_, X0 = pj * STR_;

    // stage 0: zero the p accumulator
    for (int k = t; k < 1024; k += 640) sp[k] = 0.f;

    // stage 1: load 2x32x32 patch
    for (int k = t; k < 2048; k += 640) {
        int d = k >> 10, r = k & 1023;
        int a = r >> 5, b = r & 31;
        const float* src = d ? x2 : x1;
        sP[k] = src[(Y0 + a) * W_ + (X0 + b)];
    }
    __syncthreads();

    float acc[24];
    const int u = t / 25, v = t % 25;  // output pixel for t < 625

    // stage 2: conv1 (2x8x8, 24 out ch) + bias + elu -> sH1 (bf16)
    if (t < 625) {
        #pragma unroll
        for (int o = 0; o < 24; ++o) acc[o] = 0.f;
        for (int d = 0; d < 2; ++d)
            for (int p = 0; p < 8; ++p) {
                #pragma unroll
                for (int q = 0; q < 8; ++q) {
                    float a = sP[d * 1024 + (u + p) * 32 + (v + q)];
                    const float* wr = w1t + ((d * 8 + p) * 8 + q) * 24;
                    #pragma unroll
                    for (int o = 0; o < 24; ++o) acc[o] += a * wr[o];
                }
            }
        #pragma unroll
        for (int o = 0; o < 24; ++o) {
            float hv = acc[o] + c1b[o];
            hv = hv > 0.f ? hv : expm1f(hv);
            sH1[o * 625 + t] = __float2bfloat16(hv);
        }
    }
    __syncthreads();

    // o-loop: conv2 (relu) in chunks of 12 channels, fused with deconv2
    // scatter-accumulation into per-thread registers acc[24] (= pre-elu h3).
    #pragma unroll
    for (int c = 0; c < 24; ++c) acc[c] = 0.f;

    for (int it = 0; it < 5; ++it) {
        __syncthreads();  // previous sH2 chunk fully consumed
        if (t < 441) {
            const int hy = t / 21, hx = t % 21;
            float hacc[12];
            #pragma unroll
            for (int oo = 0; oo < 12; ++oo) hacc[oo] = c2b[it * 12 + oo];
            for (int c = 0; c < 24; ++c)
                for (int p = 0; p < 5; ++p) {
                    #pragma unroll
                    for (int q = 0; q < 5; ++q) {
                        float a = __bfloat162float(sH1[c * 625 + (hy + p) * 25 + (hx + q)]);
                        const float* wr = w2t + ((c * 5 + p) * 5 + q) * 60 + it * 12;
                        #pragma unroll
                        for (int oo = 0; oo < 12; ++oo) hacc[oo] += a * wr[oo];
                    }
                }
            #pragma unroll
            for (int oo = 0; oo < 12; ++oo)
                sH2[oo * 441 + t] = fmaxf(hacc[oo], 0.f);
        }
        __syncthreads();
        if (t < 625) {
            for (int oo = 0; oo < 12; ++oo) {
                const int o = it * 12 + oo;
                #pragma unroll
                for (int dy = 0; dy < 5; ++dy) {
                    int yv = u - dy;
                    if (yv < 0 || yv >= 21) continue;
                    #pragma unroll
                    for (int dx = 0; dx < 5; ++dx) {
                        int xv = v - dx;
                        if (xv < 0 || xv >= 21) continue;
                        float a = sH2[oo * 441 + yv * 21 + xv];
                        const float* wr = dw2t + ((o * 5 + dy) * 5 + dx) * 24;
                        #pragma unroll
                        for (int c = 0; c < 24; ++c) acc[c] += a * wr[c];
                    }
                }
            }
        }
    }
    __syncthreads();  // sH1 / sH2 dead from here

    // per-patch scalars
    const float lw0 = lin_w[2 * n], lw1 = lin_w[2 * n + 1];

    // combined deconv1 x lin_w weights: wc[r=dy*8+dx][c]
    for (int k = t; k < 1536; k += 640) {
        int c = k % 24, r = k / 24;
        sWc[r * 24 + c] = lw0 * dw1[(c * 2 + 0) * 64 + r]
                        + lw1 * dw1[(c * 2 + 1) * 64 + r];
    }
    // h3 = elu(acc + deconv2_b), kept in registers
    if (t < 625) {
        #pragma unroll
        for (int c = 0; c < 24; ++c) {
            float hv = acc[c] + d2b[c];
            acc[c] = hv > 0.f ? hv : expm1f(hv);
        }
    }
    __syncthreads();

    // stage 5: deconv1 + einsum as register scatter into sp
    if (t < 625) {
        for (int r = 0; r < 64; ++r) {
            const float4* wc4 = (const float4*)(sWc + r * 24);
            float s = 0.f;
            #pragma unroll
            for (int k = 0; k < 6; ++k) {
                float4 w = wc4[k];
                s += acc[4 * k + 0] * w.x + acc[4 * k + 1] * w.y
                   + acc[4 * k + 2] * w.z + acc[4 * k + 3] * w.w;
            }
            atomicAdd(&sp[(u + (r >> 3)) * 32 + (v + (r & 7))], s);
        }
    }
    __syncthreads();

    // stage 6: overlap-add into global recon (= d_out)
    const float bias = d1b[0] * (lw0 + lw1) + lin_b[n];
    for (int k = t; k < 1024; k += 640) {
        int yy = k >> 5, xx = k & 31;
        atomicAdd(&recon[(Y0 + yy) * W_ + (X0 + xx)], sp[k] + bias);
    }
}

// ---------------------------------------------------------------------------
// Weight pre-transposes (tap-major, channel-minor so inner loops read
// contiguous wave-uniform rows -> s_load_dwordx4)
// ---------------------------------------------------------------------------
__global__ void transpose_weights(const float* __restrict__ c1w,
                                  const float* __restrict__ c2w,
                                  const float* __restrict__ d2w,
                                  float* __restrict__ w1t,
                                  float* __restrict__ w2t,
                                  float* __restrict__ dw2t)
{
    int i = blockIdx.x * blockDim.x + threadIdx.x;
    if (i < 3072) {            // w1t[r*24+o] = c1w[o*128+r], r=(d*8+p)*8+q
        int o = i % 24, r = i / 24;
        w1t[i] = c1w[o * 128 + r];
    }
    if (i < 36000) {
        // w2t[cpq*60+o] = c2w[(o*24+c)*25+pq]
        int o = i % 60, cpq = i / 60;
        int c = cpq / 25, pq = cpq % 25;
        w2t[i] = c2w[(o * 24 + c) * 25 + pq];
        // dw2t[(o*25+pq)*24+c] = d2w[(o*24+c)*25+pq]
        int c2 = i % 24, r2 = i / 24;
        int o2 = r2 / 25, pq2 = r2 % 25;
        dw2t[i] = d2w[(o2 * 24 + c2) * 25 + pq2];
    }
}

__global__ void finalize_kernel(const float* __restrict__ x2,
                                const float* __restrict__ l1w,
                                float* __restrict__ out)
{
    int i = blockIdx.x * blockDim.x + threadIdx.x;
    if (i < H_ * W_) {
        float r = out[i];
        out[i] = x2[i] - r * l1w[0];
    }
}

extern "C" void kernel_launch(void* const* d_in, const int* in_sizes, int n_in,
                              void* d_out, int out_size, void* d_ws, size_t ws_size,
                              hipStream_t stream)
{
    const float* x1  = (const float*)d_in[0];
    const float* x2  = (const float*)d_in[1];
    const float* c1w = (const float*)d_in[2];
    const float* c1b = (const float*)d_in[3];
    const float* c2w = (const float*)d_in[4];
    const float* c2b = (const float*)d_in[5];
    const float* d2w = (const float*)d_in[6];
    const float* d2b = (const float*)d_in[7];
    const float* d1w = (const float*)d_in[8];
    const float* d1b = (const float*)d_in[9];
    const float* lw  = (const float*)d_in[10];
    const float* lb  = (const float*)d_in[11];
    const float* l1w = (const float*)d_in[12];

    float* out  = (float*)d_out;
    float* w1t  = (float*)d_ws;        // 3072 f32
    float* w2t  = w1t + 3072;          // 36000 f32
    float* dw2t = w2t + 36000;         // 36000 f32  (total ws: ~300 KB)

    // recon accumulates in d_out; must start at zero every call
    hipMemsetAsync(d_out, 0, (size_t)H_ * W_ * sizeof(float), stream);

    transpose_weights<<<(36000 + 255) / 256, 256, 0, stream>>>(c1w, c2w, d2w,
                                                               w1t, w2t, dw2t);
    fused_patch_kernel<<<NPATCH_, 640, 0, stream>>>(x1, x2, c1b, c2b, d2b, d1b,
                                                    lw, lb, w1t, w2t, dw2t, d1w,
                                                    out);
    finalize_kernel<<<(H_ * W_ + 255) / 256, 256, 0, stream>>>(x2, l1w, out);
}

// Round 2
// 1764.475 us; speedup vs baseline: 5.7283x; 5.7283x over previous
//
#include <hip/hip_runtime.h>
#include <hip/hip_bf16.h>

static constexpr int H_ = 1024;
static constexpr int W_ = 1024;
static constexpr int STR_ = 16;
static constexpr int NH_ = 63;
static constexpr int NPATCH_ = NH_ * NH_;  // 3969

typedef short bf16x8 __attribute__((ext_vector_type(8)));
typedef float f32x4 __attribute__((ext_vector_type(4)));

// ---------------------------------------------------------------------------
// LDS layout (bytes):
//   sH1: [0, 50000)        625 rows x 80B   (h1 as [pixel 25x25][32ch] bf16; ch>=24 zero)
//   sH2: [50000, 113648)   442 rows x 144B  (h2 as [pixel 21x21][64ch] bf16; ch>=60 zero;
//                                            row 441 = all-zero pad row for boundary taps)
//   sP:  [50000, 58192)    overlay: raw patch f32 [2][32][32] (dead before conv2 writes)
//   After deconv2 (everything above dead):
//   h3:  [0, 70000)        625 rows x 28 f32 (stride 28 avoids bank clash; 24 used)
//   sWc: [70000, 76144)    64 x 24 f32
//   sp:  [76144, 80240)    32x32 f32 accumulator
// ---------------------------------------------------------------------------
static constexpr int SH1_STRIDE = 80;
static constexpr int SH2_BASE   = 50000;
static constexpr int SH2_STRIDE = 144;
static constexpr int ZROW_OFF   = 441 * SH2_STRIDE;   // 63504
static constexpr int H3_STRIDE  = 28;                 // floats
static constexpr int SWC_BASE   = 70000;
static constexpr int SP_ACC     = 76144;
static constexpr int LDS_BYTES  = 113648;

__device__ __forceinline__ unsigned short f2bf(float x) {
    __hip_bfloat16 b = __float2bfloat16(x);
    return __builtin_bit_cast(unsigned short, b);
}

__global__ __launch_bounds__(512, 2) void fused_patch_kernel(
    const float* __restrict__ x1, const float* __restrict__ x2,
    const float* __restrict__ c1b, const float* __restrict__ c2b,
    const float* __restrict__ d2b, const float* __restrict__ d1b,
    const float* __restrict__ lin_w, const float* __restrict__ lin_b,
    const float* __restrict__ w1t,            // [128 taps][24 ch] f32
    const unsigned short* __restrict__ w2frag,   // conv2 B frags, bf16
    const unsigned short* __restrict__ dw2frag,  // deconv2 B frags, bf16
    const float* __restrict__ dw1,            // raw deconv1_w (24,1,2,8,8)
    float* __restrict__ recon)                // = d_out (atomic overlap-add)
{
    __shared__ alignas(16) char sbuf[LDS_BYTES];
    const int n  = blockIdx.x;
    const int t  = (int)threadIdx.x;
    const int pi = n / NH_, pj = n % NH_;
    const int Y0 = pi * STR_, X0 = pj * STR_;

    float* sP = (float*)(sbuf + SH2_BASE);

    // ---- S0: zero pad-row of sH2; load 2x32x32 patch ----
    if (t < 36) ((float*)(sbuf + SH2_BASE + ZROW_OFF))[t] = 0.f;
    for (int k = t; k < 2048; k += 512) {
        int d = k >> 10, r = k & 1023, a = r >> 5, b = r & 31;
        sP[k] = (d ? x2 : x1)[(Y0 + a) * W_ + (X0 + b)];
    }
    __syncthreads();

    // ---- S1: conv1 (VALU) + elu -> sH1 bf16 rows [pixel][32ch] ----
    for (int base = 0; base < 1024; base += 512) {
        int m = base + t;
        if (m < 625) {
            int u = m / 25, v = m % 25;
            float acc[24];
            #pragma unroll
            for (int o = 0; o < 24; ++o) acc[o] = c1b[o];
            for (int dp = 0; dp < 16; ++dp) {          // dp = d*8+p
                int d = dp >> 3, p = dp & 7;
                const float* prow = sP + d * 1024 + (u + p) * 32 + v;
                const float* wr0  = w1t + dp * 8 * 24;
                #pragma unroll
                for (int q = 0; q < 8; ++q) {
                    float a = prow[q];
                    const float* wr = wr0 + q * 24;
                    #pragma unroll
                    for (int o = 0; o < 24; ++o) acc[o] = fmaf(a, wr[o], acc[o]);
                }
            }
            unsigned int pk[16];
            #pragma unroll
            for (int o2 = 0; o2 < 12; ++o2) {
                float e0 = acc[2 * o2], e1 = acc[2 * o2 + 1];
                e0 = e0 > 0.f ? e0 : expm1f(e0);
                e1 = e1 > 0.f ? e1 : expm1f(e1);
                pk[o2] = (unsigned int)f2bf(e0) | ((unsigned int)f2bf(e1) << 16);
            }
            pk[12] = pk[13] = pk[14] = pk[15] = 0u;
            uint4* row = (uint4*)(sbuf + m * SH1_STRIDE);
            row[0] = make_uint4(pk[0], pk[1], pk[2], pk[3]);
            row[1] = make_uint4(pk[4], pk[5], pk[6], pk[7]);
            row[2] = make_uint4(pk[8], pk[9], pk[10], pk[11]);
            row[3] = make_uint4(pk[12], pk[13], pk[14], pk[15]);
        }
    }
    __syncthreads();

    const int wv = t >> 6, lane = t & 63;
    const int ln15 = lane & 15, quad = lane >> 4;

    // ---- S2: conv2 as MFMA.  M=441(->448, 28 mtiles), N=64 (4 ntiles), K=32/tap, 25 taps.
    //      wave wv: ntiles {nt0, nt0+1}, mtiles mt0..mt0+6  (8 waves x 14 tiles = 112) ----
    {
        const int nt0 = (wv >> 2) * 2;
        const int mt0 = (wv & 3) * 7;
        int abase[7];
        #pragma unroll
        for (int i = 0; i < 7; ++i) {
            int m = (mt0 + i) * 16 + ln15;
            if (m > 440) m = 440;               // M-pad: read a valid row, discard at writeback
            int hy = m / 21, hx = m % 21;
            abase[i] = (hy * 25 + hx) * SH1_STRIDE + quad * 16;
        }
        const int o0 = nt0 * 16 + ln15, o1 = o0 + 16;
        const float bias0 = c2b[o0];                       // o0 <= 47 always valid
        const float bias1 = (o1 < 60) ? c2b[o1] : 0.f;

        f32x4 z4 = {0.f, 0.f, 0.f, 0.f};
        f32x4 acc2[7][2];
        #pragma unroll
        for (int i = 0; i < 7; ++i) { acc2[i][0] = z4; acc2[i][1] = z4; }

        const unsigned short* wb0 = w2frag + (nt0 * 64 + lane) * 8;
        const unsigned short* wb1 = w2frag + ((nt0 + 1) * 64 + lane) * 8;
        #pragma unroll
        for (int p = 0; p < 5; ++p) {
            #pragma unroll
            for (int q = 0; q < 5; ++q) {
                const int tap  = p * 5 + q;
                const int toff = (p * 25 + q) * SH1_STRIDE;   // compile-time const
                bf16x8 b0 = *(const bf16x8*)(wb0 + tap * 2048);
                bf16x8 b1 = *(const bf16x8*)(wb1 + tap * 2048);
                #pragma unroll
                for (int i = 0; i < 7; ++i) {
                    bf16x8 a = *(const bf16x8*)(sbuf + abase[i] + toff);
                    acc2[i][0] = __builtin_amdgcn_mfma_f32_16x16x32_bf16(a, b0, acc2[i][0], 0, 0, 0);
                    acc2[i][1] = __builtin_amdgcn_mfma_f32_16x16x32_bf16(a, b1, acc2[i][1], 0, 0, 0);
                }
            }
        }
        // writeback: relu(h2 + bias) -> sH2 bf16 [pixel][64ch] (ch 60..63 become 0)
        #pragma unroll
        for (int i = 0; i < 7; ++i) {
            #pragma unroll
            for (int r = 0; r < 4; ++r) {
                int pix = (mt0 + i) * 16 + quad * 4 + r;
                if (pix < 441) {
                    char* rowp = sbuf + SH2_BASE + pix * SH2_STRIDE;
                    *(unsigned short*)(rowp + o0 * 2) = f2bf(fmaxf(acc2[i][0][r] + bias0, 0.f));
                    *(unsigned short*)(rowp + o1 * 2) = f2bf(fmaxf(acc2[i][1][r] + bias1, 0.f));
                }
            }
        }
    }
    __syncthreads();

    // ---- S3: deconv2 as MFMA. M=625(->640, 40 mtiles), N=32 (2 ntiles), K=64 (2 kchunks), 25 taps.
    //      wave wv: mtiles wv*5..wv*5+4, both ntiles (8 waves x 10 tiles = 80) ----
    f32x4 acc3[5][2];
    {
        f32x4 z4 = {0.f, 0.f, 0.f, 0.f};
        int uarr[5], varr[5], a144[5];
        bool mval[5];
        #pragma unroll
        for (int i = 0; i < 5; ++i) {
            int m = (wv * 5 + i) * 16 + ln15;
            mval[i] = (m < 625);
            int mc = mval[i] ? m : 0;
            uarr[i] = mc / 25; varr[i] = mc % 25;
            a144[i] = (uarr[i] * 21 + varr[i]) * SH2_STRIDE;
            acc3[i][0] = z4; acc3[i][1] = z4;
        }
        const unsigned short* db = dw2frag + lane * 8;
        #pragma unroll
        for (int dy = 0; dy < 5; ++dy) {
            #pragma unroll
            for (int dx = 0; dx < 5; ++dx) {
                const int tap  = dy * 5 + dx;
                const int t2off = (dy * 21 + dx) * SH2_STRIDE;   // const
                bf16x8 b00 = *(const bf16x8*)(db + ((tap * 2 + 0) * 2 + 0) * 512);
                bf16x8 b01 = *(const bf16x8*)(db + ((tap * 2 + 0) * 2 + 1) * 512);
                bf16x8 b10 = *(const bf16x8*)(db + ((tap * 2 + 1) * 2 + 0) * 512);
                bf16x8 b11 = *(const bf16x8*)(db + ((tap * 2 + 1) * 2 + 1) * 512);
                #pragma unroll
                for (int i = 0; i < 5; ++i) {
                    int yv = uarr[i] - dy, xv = varr[i] - dx;
                    bool ok = mval[i] && ((unsigned)yv < 21u) && ((unsigned)xv < 21u);
                    int ra = ok ? (a144[i] - t2off) : ZROW_OFF;   // zero row => contributes 0
                    const char* ap = sbuf + SH2_BASE + ra + quad * 16;
                    bf16x8 a0 = *(const bf16x8*)(ap);
                    bf16x8 a1 = *(const bf16x8*)(ap + 64);
                    acc3[i][0] = __builtin_amdgcn_mfma_f32_16x16x32_bf16(a0, b00, acc3[i][0], 0, 0, 0);
                    acc3[i][1] = __builtin_amdgcn_mfma_f32_16x16x32_bf16(a0, b01, acc3[i][1], 0, 0, 0);
                    acc3[i][0] = __builtin_amdgcn_mfma_f32_16x16x32_bf16(a1, b10, acc3[i][0], 0, 0, 0);
                    acc3[i][1] = __builtin_amdgcn_mfma_f32_16x16x32_bf16(a1, b11, acc3[i][1], 0, 0, 0);
                }
            }
        }
    }
    __syncthreads();   // sH1 & sH2 fully dead from here

    // ---- S4a: h3 = elu(acc3 + d2b) -> LDS f32 [625][28]; build sWc; zero sp ----
    const float lw0 = lin_w[2 * n], lw1 = lin_w[2 * n + 1];
    float* h3  = (float*)sbuf;
    float* sWc = (float*)(sbuf + SWC_BASE);
    float* sp  = (float*)(sbuf + SP_ACC);
    {
        const int c0 = ln15, c1 = 16 + ln15;
        const float db0 = d2b[c0];
        const float db1 = (c1 < 24) ? d2b[c1] : 0.f;
        #pragma unroll
        for (int i = 0; i < 5; ++i) {
            #pragma unroll
            for (int r = 0; r < 4; ++r) {
                int pix = (wv * 5 + i) * 16 + quad * 4 + r;
                if (pix < 625) {
                    float hv = acc3[i][0][r] + db0;
                    h3[pix * H3_STRIDE + c0] = hv > 0.f ? hv : expm1f(hv);
                    if (c1 < 24) {
                        float hw = acc3[i][1][r] + db1;
                        h3[pix * H3_STRIDE + c1] = hw > 0.f ? hw : expm1f(hw);
                    }
                }
            }
        }
    }
    for (int k = t; k < 1536; k += 512) {
        int c = k % 24, r = k / 24;
        sWc[r * 24 + c] = lw0 * dw1[(c * 2 + 0) * 64 + r]
                        + lw1 * dw1[(c * 2 + 1) * 64 + r];
    }
    for (int k = t; k < 1024; k += 512) sp[k] = 0.f;
    __syncthreads();

    // ---- S4b: deconv1 + einsum as register scatter into sp ----
    for (int base = 0; base < 1024; base += 512) {
        int mm = base + t;
        if (mm < 625) {
            int u = mm / 25, v = mm % 25;
            float hreg[24];
            const float4* hr4 = (const float4*)(h3 + mm * H3_STRIDE);
            #pragma unroll
            for (int kk = 0; kk < 6; ++kk) {
                float4 x = hr4[kk];
                hreg[4 * kk + 0] = x.x; hreg[4 * kk + 1] = x.y;
                hreg[4 * kk + 2] = x.z; hreg[4 * kk + 3] = x.w;
            }
            for (int r = 0; r < 64; ++r) {
                const float4* wc4 = (const float4*)(sWc + r * 24);
                float s = 0.f;
                #pragma unroll
                for (int kk = 0; kk < 6; ++kk) {
                    float4 wq = wc4[kk];
                    s += hreg[4 * kk + 0] * wq.x + hreg[4 * kk + 1] * wq.y
                       + hreg[4 * kk + 2] * wq.z + hreg[4 * kk + 3] * wq.w;
                }
                atomicAdd(&sp[(u + (r >> 3)) * 32 + (v + (r & 7))], s);
            }
        }
    }
    __syncthreads();

    // ---- S5: overlap-add into global recon ----
    const float obias = d1b[0] * (lw0 + lw1) + lin_b[n];
    for (int k = t; k < 1024; k += 512) {
        int yy = k >> 5, xx = k & 31;
        atomicAdd(&recon[(Y0 + yy) * W_ + (X0 + xx)], sp[k] + obias);
    }
}

// ---------------------------------------------------------------------------
// Prep: w1t (f32 tap-major) + MFMA B-operand fragment arrays (bf16) in ws.
//  conv2 B frag half-index:   tap*2048 + nt*512 + lane*8 + j
//     -> B[k=c][n=o], o = nt*16 + (lane&15), c = (lane>>4)*8 + j, val = w2[o][c][p][q]
//  deconv2 B frag half-index: tap*2048 + kc*1024 + nt*512 + lane*8 + j
//     -> B[k=o2][n=c], o2 = kc*32 + (lane>>4)*8 + j, c = nt*16 + (lane&15),
//        val = d2w[(o2*24 + c)*25 + dy*5 + dx]
// ---------------------------------------------------------------------------
__global__ void prep_kernel(const float* __restrict__ c1w,
                            const float* __restrict__ c2w,
                            const float* __restrict__ d2w,
                            float* __restrict__ w1t,
                            unsigned short* __restrict__ w2frag,
                            unsigned short* __restrict__ dw2frag)
{
    int i = blockIdx.x * blockDim.x + threadIdx.x;
    if (i < 3072) {  // w1t[r*24+o] = c1w[o*128 + r]
        int o = i % 24, r = i / 24;
        w1t[i] = c1w[o * 128 + r];
    }
    if (i < 51200) {
        int j = i & 7, lane = (i >> 3) & 63;
        int ln15 = lane & 15, quad = lane >> 4;
        {   // conv2
            int nt = (i >> 9) & 3, tap = i >> 11;
            int o = nt * 16 + ln15, c = quad * 8 + j;
            float v = (o < 60 && c < 24) ? c2w[(o * 24 + c) * 25 + tap] : 0.f;
            w2frag[i] = f2bf(v);
        }
        {   // deconv2
            int nt = (i >> 9) & 1, kc = (i >> 10) & 1, tap = i >> 11;
            int k = kc * 32 + quad * 8 + j, c = nt * 16 + ln15;
            float v = (k < 60 && c < 24) ? d2w[(k * 24 + c) * 25 + tap] : 0.f;
            dw2frag[i] = f2bf(v);
        }
    }
}

__global__ void finalize_kernel(const float* __restrict__ x2,
                                const float* __restrict__ l1w,
                                float* __restrict__ out)
{
    int i = blockIdx.x * blockDim.x + threadIdx.x;
    if (i < H_ * W_) {
        float r = out[i];
        out[i] = x2[i] - r * l1w[0];
    }
}

extern "C" void kernel_launch(void* const* d_in, const int* in_sizes, int n_in,
                              void* d_out, int out_size, void* d_ws, size_t ws_size,
                              hipStream_t stream)
{
    const float* x1  = (const float*)d_in[0];
    const float* x2  = (const float*)d_in[1];
    const float* c1w = (const float*)d_in[2];
    const float* c1b = (const float*)d_in[3];
    const float* c2w = (const float*)d_in[4];
    const float* c2b = (const float*)d_in[5];
    const float* d2w = (const float*)d_in[6];
    const float* d2b = (const float*)d_in[7];
    const float* d1w = (const float*)d_in[8];
    const float* d1b = (const float*)d_in[9];
    const float* lw  = (const float*)d_in[10];
    const float* lb  = (const float*)d_in[11];
    const float* l1w = (const float*)d_in[12];

    float*          out     = (float*)d_out;
    float*          w1t     = (float*)d_ws;                               // 12288 B
    unsigned short* w2frag  = (unsigned short*)((char*)d_ws + 12288);     // 102400 B
    unsigned short* dw2frag = (unsigned short*)((char*)d_ws + 114688);    // 102400 B

    hipMemsetAsync(d_out, 0, (size_t)H_ * W_ * sizeof(float), stream);
    prep_kernel<<<100, 512, 0, stream>>>(c1w, c2w, d2w, w1t, w2frag, dw2frag);
    fused_patch_kernel<<<NPATCH_, 512, 0, stream>>>(x1, x2, c1b, c2b, d2b, d1b,
                                                    lw, lb, w1t, w2frag, dw2frag,
                                                    d1w, out);
    finalize_kernel<<<(H_ * W_ + 255) / 256, 256, 0, stream>>>(x2, l1w, out);
}

// Round 3
// 1704.100 us; speedup vs baseline: 5.9312x; 1.0354x over previous
//
#include <hip/hip_runtime.h>
#include <hip/hip_bf16.h>

static constexpr int H_ = 1024;
static constexpr int W_ = 1024;
static constexpr int STR_ = 16;
static constexpr int NH_ = 63;
static constexpr int NPATCH_ = NH_ * NH_;  // 3969

typedef short bf16x8 __attribute__((ext_vector_type(8)));
typedef short short4v __attribute__((ext_vector_type(4)));
typedef float f32x4 __attribute__((ext_vector_type(4)));

// ---------------------------------------------------------------------------
// LDS layout (bytes), total 80416 -> 2 blocks/CU (160.8KB of 160KiB):
//   sH1: [0, 45000)          625 rows x 72B  (h1 [pixel][24ch bf16 + 12 zero-pad halves])
//   sH2: [45056, 80336)      441 rows x 80B  (one 32-ch chunk of h2, bf16)
//   zrow:[80336, 80416)      80B zero row (deconv2 boundary taps; = sH2 row 441)
//   sP:  [45056, 53248)      overlay: raw patch f32 [2][32][32] (dead before conv2)
//   After deconv2 chunks (sH1/sH2 dead):
//   h3:  [0, 70000)          625 x 28 f32
//   sWc: [70016, 76160)      64 x 24 f32
//   sp:  [76160, 80256)      32x32 f32 accumulator
// ---------------------------------------------------------------------------
static constexpr int SH1_STRIDE = 72;
static constexpr int SH2_BASE   = 45056;
static constexpr int SH2_STRIDE = 80;
static constexpr int ZROW_REL   = 441 * SH2_STRIDE;   // 35280 (rel. to SH2_BASE)
static constexpr int H3_STRIDE  = 28;                 // floats
static constexpr int SWC_BASE   = 70016;
static constexpr int SP_ACC     = 76160;
static constexpr int LDS_BYTES  = 80416;

__device__ __forceinline__ unsigned short f2bf(float x) {
    __hip_bfloat16 b = __float2bfloat16(x);
    return __builtin_bit_cast(unsigned short, b);
}

__global__ __launch_bounds__(512, 4) void fused_patch_kernel(
    const float* __restrict__ x1, const float* __restrict__ x2,
    const float* __restrict__ c1b, const float* __restrict__ c2b,
    const float* __restrict__ d2b, const float* __restrict__ d1b,
    const float* __restrict__ lin_w, const float* __restrict__ lin_b,
    const float* __restrict__ w1t,               // [128 taps][24 ch] f32
    const unsigned short* __restrict__ w2frag,   // conv2 B frags, bf16
    const unsigned short* __restrict__ dw2frag,  // deconv2 B frags, bf16
    const float* __restrict__ dw1,               // raw deconv1_w (24,1,2,8,8)
    float* __restrict__ recon)                   // = d_out (atomic overlap-add)
{
    __shared__ alignas(16) char sbuf[LDS_BYTES];
    const int n  = blockIdx.x;
    const int t  = (int)threadIdx.x;
    const int pi = n / NH_, pj = n % NH_;
    const int Y0 = pi * STR_, X0 = pj * STR_;

    float* sP = (float*)(sbuf + SH2_BASE);

    // ---- S0: zero sH1 (pad halves must be 0), zero zrow, load patch ----
    for (int k = t; k < 5625; k += 512) ((uint2*)sbuf)[k] = make_uint2(0u, 0u);
    if (t < 20) ((float*)(sbuf + SH2_BASE + ZROW_REL))[t] = 0.f;
    for (int k = t; k < 2048; k += 512) {
        int d = k >> 10, r = k & 1023, a = r >> 5, b = r & 31;
        sP[k] = (d ? x2 : x1)[(Y0 + a) * W_ + (X0 + b)];
    }
    __syncthreads();

    // ---- S1: conv1 (VALU) + elu -> sH1 bf16 rows [pixel][24ch] ----
    for (int base = 0; base < 1024; base += 512) {
        int m = base + t;
        if (m < 625) {
            int u = m / 25, v = m % 25;
            float acc[24];
            #pragma unroll
            for (int o = 0; o < 24; ++o) acc[o] = c1b[o];
            for (int dp = 0; dp < 16; ++dp) {          // dp = d*8+p
                int d = dp >> 3, p = dp & 7;
                const float* prow = sP + d * 1024 + (u + p) * 32 + v;
                const float* wr0  = w1t + dp * 8 * 24;
                #pragma unroll
                for (int q = 0; q < 8; ++q) {
                    float a = prow[q];
                    const float* wr = wr0 + q * 24;
                    #pragma unroll
                    for (int o = 0; o < 24; ++o) acc[o] = fmaf(a, wr[o], acc[o]);
                }
            }
            unsigned int pk[12];
            #pragma unroll
            for (int o2 = 0; o2 < 12; ++o2) {
                float e0 = acc[2 * o2], e1 = acc[2 * o2 + 1];
                e0 = e0 > 0.f ? e0 : expm1f(e0);
                e1 = e1 > 0.f ? e1 : expm1f(e1);
                pk[o2] = (unsigned int)f2bf(e0) | ((unsigned int)f2bf(e1) << 16);
            }
            uint2* row = (uint2*)(sbuf + m * SH1_STRIDE);   // 8B-aligned
            #pragma unroll
            for (int i = 0; i < 6; ++i) row[i] = make_uint2(pk[2 * i], pk[2 * i + 1]);
        }
    }
    __syncthreads();

    const int wv = t >> 6, lane = t & 63;
    const int ln15 = lane & 15, quad = lane >> 4;

    // deconv2 accumulators persist across both K-chunks
    f32x4 acc3[5][2];
    {
        f32x4 z4 = {0.f, 0.f, 0.f, 0.f};
        #pragma unroll
        for (int i = 0; i < 5; ++i) { acc3[i][0] = z4; acc3[i][1] = z4; }
    }

    // ---- chunked conv2 (relu) <-> deconv2, K-chunks of 32 channels ----
    #pragma unroll
    for (int kc = 0; kc < 2; ++kc) {
        // conv2 chunk: M=441(->448, 28 mtiles), N=32 (both ntiles per wave),
        // waves 0..6 take 4 mtiles each.
        if (wv < 7) {
            const int mt0 = wv * 4;
            int abase[4];
            #pragma unroll
            for (int i = 0; i < 4; ++i) {
                int m = (mt0 + i) * 16 + ln15;
                if (m > 440) m = 440;            // M-pad: valid row, discarded on write
                abase[i] = ((m / 21) * 25 + (m % 21)) * SH1_STRIDE;
            }
            const int o0 = kc * 32 + ln15, o1 = o0 + 16;
            const float bias0 = c2b[o0];                      // o0 <= 47
            const float bias1 = (o1 < 60) ? c2b[o1] : 0.f;

            f32x4 z4 = {0.f, 0.f, 0.f, 0.f};
            f32x4 acc2[4][2];
            #pragma unroll
            for (int i = 0; i < 4; ++i) { acc2[i][0] = z4; acc2[i][1] = z4; }

            const unsigned short* wb = w2frag + lane * 8;
            #pragma unroll
            for (int p = 0; p < 5; ++p) {
                #pragma unroll
                for (int q = 0; q < 5; ++q) {
                    const int tap  = p * 5 + q;
                    const int toff = (p * 25 + q) * SH1_STRIDE + 0;
                    bf16x8 b0 = *(const bf16x8*)(wb + (tap * 4 + kc * 2 + 0) * 512);
                    bf16x8 b1 = *(const bf16x8*)(wb + (tap * 4 + kc * 2 + 1) * 512);
                    #pragma unroll
                    for (int i = 0; i < 4; ++i) {
                        const char* ap = sbuf + abase[i] + toff + quad * 16;
                        short4v lo = *(const short4v*)ap;         // ds_read_b64
                        short4v hi = *(const short4v*)(ap + 8);   // ds_read_b64
                        bf16x8 a = __builtin_shufflevector(lo, hi, 0, 1, 2, 3, 4, 5, 6, 7);
                        acc2[i][0] = __builtin_amdgcn_mfma_f32_16x16x32_bf16(a, b0, acc2[i][0], 0, 0, 0);
                        acc2[i][1] = __builtin_amdgcn_mfma_f32_16x16x32_bf16(a, b1, acc2[i][1], 0, 0, 0);
                    }
                }
            }
            // writeback: relu -> sH2 chunk rows [pixel][32ch bf16]
            #pragma unroll
            for (int i = 0; i < 4; ++i) {
                #pragma unroll
                for (int r = 0; r < 4; ++r) {
                    int pix = (mt0 + i) * 16 + quad * 4 + r;
                    if (pix < 441) {
                        unsigned short* rowp = (unsigned short*)(sbuf + SH2_BASE + pix * SH2_STRIDE);
                        rowp[ln15]      = f2bf(fmaxf(acc2[i][0][r] + bias0, 0.f));
                        rowp[16 + ln15] = f2bf(fmaxf(acc2[i][1][r] + bias1, 0.f));
                    }
                }
            }
        }
        __syncthreads();

        // deconv2 chunk: M=625(->640, 40 mtiles), N=32, K=32 (this chunk), 25 taps
        {
            int uarr[5], varr[5], a80[5];
            bool mval[5];
            #pragma unroll
            for (int i = 0; i < 5; ++i) {
                int m = (wv * 5 + i) * 16 + ln15;
                mval[i] = (m < 625);
                int mc = mval[i] ? m : 0;
                uarr[i] = mc / 25; varr[i] = mc % 25;
                a80[i] = (uarr[i] * 21 + varr[i]) * SH2_STRIDE;
            }
            const unsigned short* db = dw2frag + kc * 1024 + lane * 8;
            #pragma unroll
            for (int dy = 0; dy < 5; ++dy) {
                #pragma unroll
                for (int dx = 0; dx < 5; ++dx) {
                    const int tap   = dy * 5 + dx;
                    const int t2off = (dy * 21 + dx) * SH2_STRIDE;
                    bf16x8 b0 = *(const bf16x8*)(db + tap * 2048);
                    bf16x8 b1 = *(const bf16x8*)(db + tap * 2048 + 512);
                    #pragma unroll
                    for (int i = 0; i < 5; ++i) {
                        int yv = uarr[i] - dy, xv = varr[i] - dx;
                        bool ok = mval[i] && ((unsigned)yv < 21u) && ((unsigned)xv < 21u);
                        int ra = ok ? (a80[i] - t2off) : ZROW_REL;  // zero row -> +0
                        const char* ap = sbuf + SH2_BASE + ra + quad * 16;
                        bf16x8 a = *(const bf16x8*)ap;              // ds_read_b128
                        acc3[i][0] = __builtin_amdgcn_mfma_f32_16x16x32_bf16(a, b0, acc3[i][0], 0, 0, 0);
                        acc3[i][1] = __builtin_amdgcn_mfma_f32_16x16x32_bf16(a, b1, acc3[i][1], 0, 0, 0);
                    }
                }
            }
        }
        __syncthreads();
    }

    // ---- S4a: h3 = elu(acc3 + d2b) -> LDS f32 [625][28]; build sWc; zero sp ----
    const float lw0 = lin_w[2 * n], lw1 = lin_w[2 * n + 1];
    float* h3  = (float*)sbuf;
    float* sWc = (float*)(sbuf + SWC_BASE);
    float* sp  = (float*)(sbuf + SP_ACC);
    {
        const int c0 = ln15, c1 = 16 + ln15;
        const float db0 = d2b[c0];
        const float db1 = (c1 < 24) ? d2b[c1] : 0.f;
        #pragma unroll
        for (int i = 0; i < 5; ++i) {
            #pragma unroll
            for (int r = 0; r < 4; ++r) {
                int pix = (wv * 5 + i) * 16 + quad * 4 + r;
                if (pix < 625) {
                    float hv = acc3[i][0][r] + db0;
                    h3[pix * H3_STRIDE + c0] = hv > 0.f ? hv : expm1f(hv);
                    if (c1 < 24) {
                        float hw = acc3[i][1][r] + db1;
                        h3[pix * H3_STRIDE + c1] = hw > 0.f ? hw : expm1f(hw);
                    }
                }
            }
        }
    }
    for (int k = t; k < 1536; k += 512) {
        int c = k % 24, r = k / 24;
        sWc[r * 24 + c] = lw0 * dw1[(c * 2 + 0) * 64 + r]
                        + lw1 * dw1[(c * 2 + 1) * 64 + r];
    }
    for (int k = t; k < 1024; k += 512) sp[k] = 0.f;
    __syncthreads();

    // ---- S4b: deconv1 + einsum as register scatter into sp ----
    for (int base = 0; base < 1024; base += 512) {
        int mm = base + t;
        if (mm < 625) {
            int u = mm / 25, v = mm % 25;
            float hreg[24];
            const float4* hr4 = (const float4*)(h3 + mm * H3_STRIDE);
            #pragma unroll
            for (int kk = 0; kk < 6; ++kk) {
                float4 x = hr4[kk];
                hreg[4 * kk + 0] = x.x; hreg[4 * kk + 1] = x.y;
                hreg[4 * kk + 2] = x.z; hreg[4 * kk + 3] = x.w;
            }
            for (int r = 0; r < 64; ++r) {
                const float4* wc4 = (const float4*)(sWc + r * 24);
                float s = 0.f;
                #pragma unroll
                for (int kk = 0; kk < 6; ++kk) {
                    float4 wq = wc4[kk];
                    s += hreg[4 * kk + 0] * wq.x + hreg[4 * kk + 1] * wq.y
                       + hreg[4 * kk + 2] * wq.z + hreg[4 * kk + 3] * wq.w;
                }
                atomicAdd(&sp[(u + (r >> 3)) * 32 + (v + (r & 7))], s);
            }
        }
    }
    __syncthreads();

    // ---- S5: overlap-add into global recon ----
    const float obias = d1b[0] * (lw0 + lw1) + lin_b[n];
    for (int k = t; k < 1024; k += 512) {
        int yy = k >> 5, xx = k & 31;
        atomicAdd(&recon[(Y0 + yy) * W_ + (X0 + xx)], sp[k] + obias);
    }
}

// ---------------------------------------------------------------------------
// Prep (unchanged layouts from R2):
//  conv2 B frag half-index:   tap*2048 + nt*512 + lane*8 + j
//     -> o = nt*16 + (lane&15), c = (lane>>4)*8 + j, val = w2[o][c][p][q]
//  deconv2 B frag half-index: tap*2048 + kc*1024 + nt*512 + lane*8 + j
//     -> k = kc*32 + (lane>>4)*8 + j, c = nt*16 + (lane&15)
// ---------------------------------------------------------------------------
__global__ void prep_kernel(const float* __restrict__ c1w,
                            const float* __restrict__ c2w,
                            const float* __restrict__ d2w,
                            float* __restrict__ w1t,
                            unsigned short* __restrict__ w2frag,
                            unsigned short* __restrict__ dw2frag)
{
    int i = blockIdx.x * blockDim.x + threadIdx.x;
    if (i < 3072) {  // w1t[r*24+o] = c1w[o*128 + r]
        int o = i % 24, r = i / 24;
        w1t[i] = c1w[o * 128 + r];
    }
    if (i < 51200) {
        int j = i & 7, lane = (i >> 3) & 63;
        int ln15 = lane & 15, quad = lane >> 4;
        {   // conv2
            int nt = (i >> 9) & 3, tap = i >> 11;
            int o = nt * 16 + ln15, c = quad * 8 + j;
            float v = (o < 60 && c < 24) ? c2w[(o * 24 + c) * 25 + tap] : 0.f;
            w2frag[i] = f2bf(v);
        }
        {   // deconv2
            int nt = (i >> 9) & 1, kc = (i >> 10) & 1, tap = i >> 11;
            int k = kc * 32 + quad * 8 + j, c = nt * 16 + ln15;
            float v = (k < 60 && c < 24) ? d2w[(k * 24 + c) * 25 + tap] : 0.f;
            dw2frag[i] = f2bf(v);
        }
    }
}

__global__ void finalize_kernel(const float* __restrict__ x2,
                                const float* __restrict__ l1w,
                                float* __restrict__ out)
{
    int i = blockIdx.x * blockDim.x + threadIdx.x;
    if (i < H_ * W_) {
        float r = out[i];
        out[i] = x2[i] - r * l1w[0];
    }
}

extern "C" void kernel_launch(void* const* d_in, const int* in_sizes, int n_in,
                              void* d_out, int out_size, void* d_ws, size_t ws_size,
                              hipStream_t stream)
{
    const float* x1  = (const float*)d_in[0];
    const float* x2  = (const float*)d_in[1];
    const float* c1w = (const float*)d_in[2];
    const float* c1b = (const float*)d_in[3];
    const float* c2w = (const float*)d_in[4];
    const float* c2b = (const float*)d_in[5];
    const float* d2w = (const float*)d_in[6];
    const float* d2b = (const float*)d_in[7];
    const float* d1w = (const float*)d_in[8];
    const float* d1b = (const float*)d_in[9];
    const float* lw  = (const float*)d_in[10];
    const float* lb  = (const float*)d_in[11];
    const float* l1w = (const float*)d_in[12];

    float*          out     = (float*)d_out;
    float*          w1t     = (float*)d_ws;                               // 12288 B
    unsigned short* w2frag  = (unsigned short*)((char*)d_ws + 12288);     // 102400 B
    unsigned short* dw2frag = (unsigned short*)((char*)d_ws + 114688);    // 102400 B

    hipMemsetAsync(d_out, 0, (size_t)H_ * W_ * sizeof(float), stream);
    prep_kernel<<<100, 512, 0, stream>>>(c1w, c2w, d2w, w1t, w2frag, dw2frag);
    fused_patch_kernel<<<NPATCH_, 512, 0, stream>>>(x1, x2, c1b, c2b, d2b, d1b,
                                                    lw, lb, w1t, w2frag, dw2frag,
                                                    d1w, out);
    finalize_kernel<<<(H_ * W_ + 255) / 256, 256, 0, stream>>>(x2, l1w, out);
}

// Round 4
// 1528.421 us; speedup vs baseline: 6.6130x; 1.1149x over previous
//
#include <hip/hip_runtime.h>
#include <hip/hip_bf16.h>

static constexpr int H_ = 1024;
static constexpr int W_ = 1024;
static constexpr int STR_ = 16;
static constexpr int NH_ = 63;
static constexpr int NPATCH_ = NH_ * NH_;  // 3969

typedef short bf16x8 __attribute__((ext_vector_type(8)));
typedef short short4v __attribute__((ext_vector_type(4)));
typedef float f32x4 __attribute__((ext_vector_type(4)));

// ---------------------------------------------------------------------------
// LDS layout (bytes), total 80416 -> 2 blocks/CU:
//   sH1: [0, 45000)        625 rows x 72B  (h1 [pixel y*25+x][32ch bf16 + 4 pad])
//   sH2: [45056, 80416)    442 rows x 80B  (one 32-ch chunk of h2 bf16; row 441 = zero row)
//   sPb overlay in sH2 region (dead before conv2 writes):
//     copy0 [45056, 50176)  patch bf16 [2][32][40]
//     copy1 [50176, 55296)  same, shifted left 1 column (copy1[x] = patch[x+1])
//   After deconv2 (sH1/sH2 dead):
//     h3:  [0, 50000)       625 rows x 80B  ([pixel][32ch bf16], ch 24..31 = 0)
//     sWc: [51200, 56320)   64 rows x 80B   (bf16 [r][32c], c 24..31 = 0)
//     sp:  [56320, 60416)   32x32 f32 accumulator
// ---------------------------------------------------------------------------
static constexpr int SH1_STRIDE = 72;
static constexpr int SH2_BASE   = 45056;
static constexpr int SH2_STRIDE = 80;
static constexpr int ZROW_REL   = 441 * SH2_STRIDE;   // 35280
static constexpr int SPB0       = 45056;
static constexpr int SPB1       = 50176;
static constexpr int H3_STRIDE  = 80;                 // bytes
static constexpr int SWC_BASE   = 51200;
static constexpr int SP_ACC     = 56320;
static constexpr int LDS_BYTES  = 80416;

__device__ __forceinline__ unsigned short f2bf(float x) {
    __hip_bfloat16 b = __float2bfloat16(x);
    return __builtin_bit_cast(unsigned short, b);
}

__global__ __launch_bounds__(512, 2) void fused_patch_kernel(
    const float* __restrict__ x1, const float* __restrict__ x2,
    const float* __restrict__ c1b, const float* __restrict__ c2b,
    const float* __restrict__ d2b, const float* __restrict__ d1b,
    const float* __restrict__ lin_w, const float* __restrict__ lin_b,
    const unsigned short* __restrict__ w1frag,   // conv1 B frags, bf16
    const unsigned short* __restrict__ w2frag,   // conv2 B frags, bf16
    const unsigned short* __restrict__ dw2frag,  // deconv2 B frags, bf16
    const float* __restrict__ dw1,               // raw deconv1_w (24,1,2,8,8)
    float* __restrict__ recon)                   // = d_out (atomic overlap-add)
{
    __shared__ alignas(16) char sbuf[LDS_BYTES];
    const int n  = blockIdx.x;
    const int t  = (int)threadIdx.x;
    const int pi = n / NH_, pj = n % NH_;
    const int Y0 = pi * STR_, X0 = pj * STR_;
    const int wv = t >> 6, lane = t & 63;
    const int ln15 = lane & 15, quad = lane >> 4;

    // ---- S0: zero zrow; load patch f32 -> bf16, two parity copies ----
    if (t < 20) ((float*)(sbuf + SH2_BASE + ZROW_REL))[t] = 0.f;
    for (int k = t; k < 2048; k += 512) {
        int d = k >> 10, r = k & 1023, y = r >> 5, x = r & 31;
        unsigned short b = f2bf((d ? x2 : x1)[(Y0 + y) * W_ + (X0 + x)]);
        int row = (d * 32 + y) * 40;
        ((unsigned short*)(sbuf + SPB0))[row + x] = b;
        if (x > 0) ((unsigned short*)(sbuf + SPB1))[row + x - 1] = b;
    }
    __syncthreads();

    // ---- S1: conv1 as MFMA. M=800 (25 cols x 32 rows, col-major tiles),
    //      N=32 (24 ch + 8 zero-pad), K=128 (4 kchunks). 50 mtiles. ----
    {
        bf16x8 bw[4][2];
        #pragma unroll
        for (int kc = 0; kc < 4; ++kc)
            #pragma unroll
            for (int nt = 0; nt < 2; ++nt)
                bw[kc][nt] = *(const bf16x8*)(w1frag + (((kc * 2 + nt) * 64) + lane) * 8);

        for (int tl = wv; tl < 50; tl += 8) {
            const int vcol = tl >> 1, ubase = (tl & 1) * 16;
            const int u = ubase + ln15;                 // A-row index (may be >=25: junk, discarded)
            const char* abase = sbuf + ((vcol & 1) ? SPB1 : SPB0) + (vcol & ~1) * 2;
            f32x4 acc[2];
            acc[0] = (f32x4){0.f, 0.f, 0.f, 0.f};
            acc[1] = (f32x4){0.f, 0.f, 0.f, 0.f};
            #pragma unroll
            for (int kc = 0; kc < 4; ++kc) {
                const int idx8 = kc * 4 + quad;         // = k/8
                const int dd = idx8 >> 3, pp = idx8 & 7;
                const unsigned int* ap = (const unsigned int*)(abase + (dd * 32 + u + pp) * 80);
                union { unsigned int u4[4]; bf16x8 v; } af;
                af.u4[0] = ap[0]; af.u4[1] = ap[1]; af.u4[2] = ap[2]; af.u4[3] = ap[3];
                acc[0] = __builtin_amdgcn_mfma_f32_16x16x32_bf16(af.v, bw[kc][0], acc[0], 0, 0, 0);
                acc[1] = __builtin_amdgcn_mfma_f32_16x16x32_bf16(af.v, bw[kc][1], acc[1], 0, 0, 0);
            }
            // writeback: elu(h1 + bias) -> sH1[(u*25+v)*72 + c*2]
            #pragma unroll
            for (int ntp = 0; ntp < 2; ++ntp) {
                const int c = ntp * 16 + ln15;
                const float bias = (c < 24) ? c1b[c] : 0.f;
                #pragma unroll
                for (int r = 0; r < 4; ++r) {
                    int uu = ubase + quad * 4 + r;
                    if (uu < 25) {
                        float hv = acc[ntp][r] + bias;
                        hv = hv > 0.f ? hv : expm1f(hv);
                        *(unsigned short*)(sbuf + (uu * 25 + vcol) * SH1_STRIDE + c * 2) = f2bf(hv);
                    }
                }
            }
        }
    }
    __syncthreads();

    // deconv2 accumulators persist across both K-chunks
    f32x4 acc3[5][2];
    {
        f32x4 z4 = {0.f, 0.f, 0.f, 0.f};
        #pragma unroll
        for (int i = 0; i < 5; ++i) { acc3[i][0] = z4; acc3[i][1] = z4; }
    }

    // ---- chunked conv2 (relu) <-> deconv2, K-chunks of 32 channels ----
    #pragma unroll
    for (int kc = 0; kc < 2; ++kc) {
        // conv2 chunk: M=441(->448, 28 mtiles), N=32; waves 0..6 take 4 mtiles each
        if (wv < 7) {
            const int mt0 = wv * 4;
            int abase[4];
            #pragma unroll
            for (int i = 0; i < 4; ++i) {
                int m = (mt0 + i) * 16 + ln15;
                if (m > 440) m = 440;            // M-pad: valid row, discarded on write
                abase[i] = ((m / 21) * 25 + (m % 21)) * SH1_STRIDE;
            }
            const int o0 = kc * 32 + ln15, o1 = o0 + 16;
            const float bias0 = c2b[o0];                      // o0 <= 47
            const float bias1 = (o1 < 60) ? c2b[o1] : 0.f;

            f32x4 z4 = {0.f, 0.f, 0.f, 0.f};
            f32x4 acc2[4][2];
            #pragma unroll
            for (int i = 0; i < 4; ++i) { acc2[i][0] = z4; acc2[i][1] = z4; }

            const unsigned short* wb = w2frag + lane * 8;
            #pragma unroll
            for (int p = 0; p < 5; ++p) {
                #pragma unroll
                for (int q = 0; q < 5; ++q) {
                    const int tap  = p * 5 + q;
                    const int toff = (p * 25 + q) * SH1_STRIDE;
                    bf16x8 b0 = *(const bf16x8*)(wb + (tap * 4 + kc * 2 + 0) * 512);
                    bf16x8 b1 = *(const bf16x8*)(wb + (tap * 4 + kc * 2 + 1) * 512);
                    #pragma unroll
                    for (int i = 0; i < 4; ++i) {
                        const char* ap = sbuf + abase[i] + toff + quad * 16;
                        short4v lo = *(const short4v*)ap;         // ds_read_b64
                        short4v hi = *(const short4v*)(ap + 8);   // ds_read_b64
                        bf16x8 a = __builtin_shufflevector(lo, hi, 0, 1, 2, 3, 4, 5, 6, 7);
                        acc2[i][0] = __builtin_amdgcn_mfma_f32_16x16x32_bf16(a, b0, acc2[i][0], 0, 0, 0);
                        acc2[i][1] = __builtin_amdgcn_mfma_f32_16x16x32_bf16(a, b1, acc2[i][1], 0, 0, 0);
                    }
                }
            }
            // writeback: relu -> sH2 chunk rows [pixel][32ch bf16]
            #pragma unroll
            for (int i = 0; i < 4; ++i) {
                #pragma unroll
                for (int r = 0; r < 4; ++r) {
                    int pix = (mt0 + i) * 16 + quad * 4 + r;
                    if (pix < 441) {
                        unsigned short* rowp = (unsigned short*)(sbuf + SH2_BASE + pix * SH2_STRIDE);
                        rowp[ln15]      = f2bf(fmaxf(acc2[i][0][r] + bias0, 0.f));
                        rowp[16 + ln15] = f2bf(fmaxf(acc2[i][1][r] + bias1, 0.f));
                    }
                }
            }
        }
        __syncthreads();

        // deconv2 chunk: M=625(->640, 40 mtiles), N=32, K=32 (this chunk), 25 taps
        {
            int uarr[5], varr[5], a80[5];
            bool mval[5];
            #pragma unroll
            for (int i = 0; i < 5; ++i) {
                int m = (wv * 5 + i) * 16 + ln15;
                mval[i] = (m < 625);
                int mc = mval[i] ? m : 0;
                uarr[i] = mc / 25; varr[i] = mc % 25;
                a80[i] = (uarr[i] * 21 + varr[i]) * SH2_STRIDE;
            }
            const unsigned short* db = dw2frag + kc * 1024 + lane * 8;
            #pragma unroll
            for (int dy = 0; dy < 5; ++dy) {
                #pragma unroll
                for (int dx = 0; dx < 5; ++dx) {
                    const int tap   = dy * 5 + dx;
                    const int t2off = (dy * 21 + dx) * SH2_STRIDE;
                    bf16x8 b0 = *(const bf16x8*)(db + tap * 2048);
                    bf16x8 b1 = *(const bf16x8*)(db + tap * 2048 + 512);
                    #pragma unroll
                    for (int i = 0; i < 5; ++i) {
                        int yv = uarr[i] - dy, xv = varr[i] - dx;
                        bool ok = mval[i] && ((unsigned)yv < 21u) && ((unsigned)xv < 21u);
                        int ra = ok ? (a80[i] - t2off) : ZROW_REL;  // zero row -> +0
                        const char* ap = sbuf + SH2_BASE + ra + quad * 16;
                        bf16x8 a = *(const bf16x8*)ap;              // ds_read_b128
                        acc3[i][0] = __builtin_amdgcn_mfma_f32_16x16x32_bf16(a, b0, acc3[i][0], 0, 0, 0);
                        acc3[i][1] = __builtin_amdgcn_mfma_f32_16x16x32_bf16(a, b1, acc3[i][1], 0, 0, 0);
                    }
                }
            }
        }
        __syncthreads();
    }

    // ---- S4a: h3 = elu(acc3 + d2b) -> bf16 [625][32ch] stride 80B;
    //           build sWc (bf16, K-padded); zero sp ----
    const float lw0 = lin_w[2 * n], lw1 = lin_w[2 * n + 1];
    float* sp = (float*)(sbuf + SP_ACC);
    {
        const int c0 = ln15, c1 = 16 + ln15;
        const float db0 = d2b[c0];
        const float db1 = (c1 < 24) ? d2b[c1] : 0.f;   // c1>=24: acc3=0, bias 0 -> writes exact 0
        #pragma unroll
        for (int i = 0; i < 5; ++i) {
            #pragma unroll
            for (int r = 0; r < 4; ++r) {
                int pix = (wv * 5 + i) * 16 + quad * 4 + r;
                if (pix < 625) {
                    float hv = acc3[i][0][r] + db0;
                    hv = hv > 0.f ? hv : expm1f(hv);
                    float hw = acc3[i][1][r] + db1;
                    hw = hw > 0.f ? hw : expm1f(hw);
                    unsigned short* rowp = (unsigned short*)(sbuf + pix * H3_STRIDE);
                    rowp[c0] = f2bf(hv);
                    rowp[c1] = f2bf(hw);
                }
            }
        }
    }
    for (int k = t; k < 2048; k += 512) {   // sWc: 64 r x 32 c
        int r = k >> 5, c = k & 31;
        float v = 0.f;
        if (c < 24)
            v = lw0 * dw1[(c * 2 + 0) * 64 + r] + lw1 * dw1[(c * 2 + 1) * 64 + r];
        ((unsigned short*)(sbuf + SWC_BASE))[r * 40 + c] = f2bf(v);
    }
    for (int k = t; k < 1024; k += 512) sp[k] = 0.f;
    __syncthreads();

    // ---- S4b: epilogue GEMM p[m=pix][r] = sum_c h3[m][c]*wc[r][c] (K=32),
    //           then scatter-add into sp via LDS atomics ----
    #pragma unroll
    for (int pass = 0; pass < 2; ++pass) {
        bf16x8 wb0 = *(const bf16x8*)(sbuf + SWC_BASE + ((pass * 2 + 0) * 16 + ln15) * 80 + quad * 16);
        bf16x8 wb1 = *(const bf16x8*)(sbuf + SWC_BASE + ((pass * 2 + 1) * 16 + ln15) * 80 + quad * 16);
        f32x4 acc4[5][2];
        {
            f32x4 z4 = {0.f, 0.f, 0.f, 0.f};
            #pragma unroll
            for (int i = 0; i < 5; ++i) { acc4[i][0] = z4; acc4[i][1] = z4; }
        }
        #pragma unroll
        for (int i = 0; i < 5; ++i) {
            int m = (wv * 5 + i) * 16 + ln15;
            if (m > 624) m = 624;
            bf16x8 a = *(const bf16x8*)(sbuf + m * H3_STRIDE + quad * 16);
            acc4[i][0] = __builtin_amdgcn_mfma_f32_16x16x32_bf16(a, wb0, acc4[i][0], 0, 0, 0);
            acc4[i][1] = __builtin_amdgcn_mfma_f32_16x16x32_bf16(a, wb1, acc4[i][1], 0, 0, 0);
        }
        #pragma unroll
        for (int i = 0; i < 5; ++i) {
            #pragma unroll
            for (int r = 0; r < 4; ++r) {
                int pix = (wv * 5 + i) * 16 + quad * 4 + r;
                if (pix < 625) {
                    int u = pix / 25, v = pix % 25;
                    #pragma unroll
                    for (int ntp = 0; ntp < 2; ++ntp) {
                        int rv = (pass * 2 + ntp) * 16 + ln15;
                        atomicAdd(&sp[(u + (rv >> 3)) * 32 + v + (rv & 7)], acc4[i][ntp][r]);
                    }
                }
            }
        }
    }
    __syncthreads();

    // ---- S5: overlap-add into global recon ----
    const float obias = d1b[0] * (lw0 + lw1) + lin_b[n];
    for (int k = t; k < 1024; k += 512) {
        int yy = k >> 5, xx = k & 31;
        atomicAdd(&recon[(Y0 + yy) * W_ + (X0 + xx)], sp[k] + obias);
    }
}

// ---------------------------------------------------------------------------
// Prep: MFMA B-operand fragment arrays (bf16) in ws.
//  conv1:   i = (kc*2+nt)*512 + lane*8 + j -> n=nt*16+(lane&15), k=kc*32+(lane>>4)*8+j
//           val = (n<24) ? c1w[n*128+k] : 0
//  conv2:   tap*2048 + nt*512 + lane*8 + j -> o=nt*16+ln15, c=quad*8+j
//  deconv2: tap*2048 + kc*1024 + nt*512 + lane*8 + j -> k=kc*32+quad*8+j, c=nt*16+ln15
// ---------------------------------------------------------------------------
__global__ void prep_kernel(const float* __restrict__ c1w,
                            const float* __restrict__ c2w,
                            const float* __restrict__ d2w,
                            unsigned short* __restrict__ w1frag,
                            unsigned short* __restrict__ w2frag,
                            unsigned short* __restrict__ dw2frag)
{
    int i = blockIdx.x * blockDim.x + threadIdx.x;
    if (i < 51200) {
        int j = i & 7, lane = (i >> 3) & 63;
        int ln15 = lane & 15, quad = lane >> 4;
        if (i < 4096) {   // conv1
            int g = i >> 9;                   // = kc*2 + nt
            int kc = g >> 1, nt = g & 1;
            int nn = nt * 16 + ln15, k = kc * 32 + quad * 8 + j;
            w1frag[i] = f2bf((nn < 24) ? c1w[nn * 128 + k] : 0.f);
        }
        {   // conv2
            int nt = (i >> 9) & 3, tap = i >> 11;
            int o = nt * 16 + ln15, c = quad * 8 + j;
            float v = (o < 60 && c < 24) ? c2w[(o * 24 + c) * 25 + tap] : 0.f;
            w2frag[i] = f2bf(v);
        }
        {   // deconv2
            int nt = (i >> 9) & 1, kc = (i >> 10) & 1, tap = i >> 11;
            int k = kc * 32 + quad * 8 + j, c = nt * 16 + ln15;
            float v = (k < 60 && c < 24) ? d2w[(k * 24 + c) * 25 + tap] : 0.f;
            dw2frag[i] = f2bf(v);
        }
    }
}

__global__ void finalize_kernel(const float* __restrict__ x2,
                                const float* __restrict__ l1w,
                                float* __restrict__ out)
{
    int i = blockIdx.x * blockDim.x + threadIdx.x;
    if (i < H_ * W_) {
        float r = out[i];
        out[i] = x2[i] - r * l1w[0];
    }
}

extern "C" void kernel_launch(void* const* d_in, const int* in_sizes, int n_in,
                              void* d_out, int out_size, void* d_ws, size_t ws_size,
                              hipStream_t stream)
{
    const float* x1  = (const float*)d_in[0];
    const float* x2  = (const float*)d_in[1];
    const float* c1w = (const float*)d_in[2];
    const float* c1b = (const float*)d_in[3];
    const float* c2w = (const float*)d_in[4];
    const float* c2b = (const float*)d_in[5];
    const float* d2w = (const float*)d_in[6];
    const float* d2b = (const float*)d_in[7];
    const float* d1w = (const float*)d_in[8];
    const float* d1b = (const float*)d_in[9];
    const float* lw  = (const float*)d_in[10];
    const float* lb  = (const float*)d_in[11];
    const float* l1w = (const float*)d_in[12];

    float*          out     = (float*)d_out;
    unsigned short* w1frag  = (unsigned short*)d_ws;                      // 8192 B
    unsigned short* w2frag  = (unsigned short*)((char*)d_ws + 8192);      // 102400 B
    unsigned short* dw2frag = (unsigned short*)((char*)d_ws + 110592);    // 102400 B

    hipMemsetAsync(d_out, 0, (size_t)H_ * W_ * sizeof(float), stream);
    prep_kernel<<<100, 512, 0, stream>>>(c1w, c2w, d2w, w1frag, w2frag, dw2frag);
    fused_patch_kernel<<<NPATCH_, 512, 0, stream>>>(x1, x2, c1b, c2b, d2b, d1b,
                                                    lw, lb, w1frag, w2frag, dw2frag,
                                                    d1w, out);
    finalize_kernel<<<(H_ * W_ + 255) / 256, 256, 0, stream>>>(x2, l1w, out);
}

// Round 5
// 1435.378 us; speedup vs baseline: 7.0416x; 1.0648x over previous
//
#include <hip/hip_runtime.h>
#include <hip/hip_bf16.h>

static constexpr int H_ = 1024;
static constexpr int W_ = 1024;
static constexpr int STR_ = 16;
static constexpr int NH_ = 63;
static constexpr int NPATCH_ = NH_ * NH_;  // 3969

typedef short bf16x8 __attribute__((ext_vector_type(8)));
typedef short short4v __attribute__((ext_vector_type(4)));
typedef float f32x4 __attribute__((ext_vector_type(4)));

// ---------------------------------------------------------------------------
// LDS layout (bytes), total 83072 -> single 1024-thread block (16 waves/CU):
//   sH1: [0, 30000)         625 rows x 48B ([pixel][24ch bf16], NO pad --
//                           conv2 K-reads beyond 24ch hit next row: finite
//                           garbage x B-frag zeros (k>=24) = 0)
//   sH2: [30016, 83056)     442 rows x 120B ([pixel][60ch bf16]; row 441 = zero row)
//   patch copies overlay sH2 head (dead before conv2 writes):
//     copy0 [30016, 35136)  patch bf16 [2][32][40]
//     copy1 [35136, 40256)  same, shifted left 1 column
//   After deconv2 (sH1/sH2 dead):
//     h3:  [0, 30000)       625 rows x 48B ([pixel][24ch bf16])
//     sWc: [30016, 34112)   64 rows x 64B (bf16 [r][32c], c>=24 zero)
//     sp:  [34112, 38208)   32x32 f32 accumulator
// ---------------------------------------------------------------------------
static constexpr int SH1_STRIDE = 48;
static constexpr int SH2_BASE   = 30016;
static constexpr int SH2_STRIDE = 120;
static constexpr int ZROW_REL   = 441 * SH2_STRIDE;   // 52920
static constexpr int SPB0       = 30016;
static constexpr int SPB1       = 35136;
static constexpr int SWC_BASE   = 30016;
static constexpr int SP_ACC     = 34112;
static constexpr int LDS_BYTES  = 83072;              // incl. 16B tail pad for zrow overread

__device__ __forceinline__ unsigned short f2bf(float x) {
    __hip_bfloat16 b = __float2bfloat16(x);
    return __builtin_bit_cast(unsigned short, b);
}

__device__ __forceinline__ f32x4 mfma_bf16(bf16x8 a, bf16x8 b, f32x4 c) {
    return __builtin_amdgcn_mfma_f32_16x16x32_bf16(a, b, c, 0, 0, 0);
}

__global__ __launch_bounds__(1024, 4) void fused_patch_kernel(
    const float* __restrict__ x1, const float* __restrict__ x2,
    const float* __restrict__ c1b, const float* __restrict__ c2b,
    const float* __restrict__ d2b, const float* __restrict__ d1b,
    const float* __restrict__ lin_w, const float* __restrict__ lin_b,
    const unsigned short* __restrict__ w1frag,   // conv1 B frags, bf16
    const unsigned short* __restrict__ w2frag,   // conv2 B frags, bf16
    const unsigned short* __restrict__ dw2frag,  // deconv2 B frags, bf16
    const float* __restrict__ dw1,               // raw deconv1_w (24,1,2,8,8)
    float* __restrict__ recon)                   // = d_out (atomic overlap-add)
{
    __shared__ alignas(16) char sbuf[LDS_BYTES];
    const int n  = blockIdx.x;
    const int t  = (int)threadIdx.x;
    const int pi = n / NH_, pj = n % NH_;
    const int Y0 = pi * STR_, X0 = pj * STR_;
    const int wv = t >> 6, lane = t & 63;
    const int ln15 = lane & 15, quad = lane >> 4;

    // ---- S0: zero zrow; load patch f32 -> bf16, two parity copies ----
    if (t < 30) ((float*)(sbuf + SH2_BASE + ZROW_REL))[t] = 0.f;
    for (int k = t; k < 2048; k += 1024) {
        int d = k >> 10, r = k & 1023, y = r >> 5, x = r & 31;
        unsigned short b = f2bf((d ? x2 : x1)[(Y0 + y) * W_ + (X0 + x)]);
        int row = (d * 32 + y) * 40;
        ((unsigned short*)(sbuf + SPB0))[row + x] = b;
        if (x > 0) ((unsigned short*)(sbuf + SPB1))[row + x - 1] = b;
    }
    __syncthreads();

    // ---- S1: conv1 as MFMA. M=800 (25 cols x 32 rows), N=32, K=128. 50 mtiles ----
    for (int tl = wv; tl < 50; tl += 16) {
        const int vcol = tl >> 1, ubase = (tl & 1) * 16;
        const int u = ubase + ln15;                 // may be >=25: junk row, discarded
        const char* abase = sbuf + ((vcol & 1) ? SPB1 : SPB0) + (vcol & ~1) * 2;
        f32x4 acc[2];
        acc[0] = (f32x4){0.f, 0.f, 0.f, 0.f};
        acc[1] = (f32x4){0.f, 0.f, 0.f, 0.f};
        #pragma unroll
        for (int kc = 0; kc < 4; ++kc) {
            const int idx8 = kc * 4 + quad;         // = k/8
            const int dd = idx8 >> 3, pp = idx8 & 7;
            const unsigned int* ap = (const unsigned int*)(abase + (dd * 32 + u + pp) * 80);
            union { unsigned int u4[4]; bf16x8 v; } af;
            af.u4[0] = ap[0]; af.u4[1] = ap[1]; af.u4[2] = ap[2]; af.u4[3] = ap[3];
            bf16x8 b0 = *(const bf16x8*)(w1frag + (((kc * 2 + 0) * 64) + lane) * 8);
            bf16x8 b1 = *(const bf16x8*)(w1frag + (((kc * 2 + 1) * 64) + lane) * 8);
            acc[0] = mfma_bf16(af.v, b0, acc[0]);
            acc[1] = mfma_bf16(af.v, b1, acc[1]);
        }
        #pragma unroll
        for (int ntp = 0; ntp < 2; ++ntp) {
            const int c = ntp * 16 + ln15;
            if (c < 24) {
                const float bias = c1b[c];
                #pragma unroll
                for (int r = 0; r < 4; ++r) {
                    int uu = ubase + quad * 4 + r;
                    if (uu < 25) {
                        float hv = acc[ntp][r] + bias;
                        hv = hv > 0.f ? hv : expm1f(hv);
                        *(unsigned short*)(sbuf + (uu * 25 + vcol) * SH1_STRIDE + c * 2) = f2bf(hv);
                    }
                }
            }
        }
    }
    __syncthreads();

    // ---- S2: conv2 as MFMA. M=441(->448, 28 mtiles), N=64 (60+4 pad), K=32
    //      (24 real ch + garbage x B-zeros). Waves 0..13: mtiles {wv, wv+14} ----
    if (wv < 14) {
        int abase2[2];
        #pragma unroll
        for (int i = 0; i < 2; ++i) {
            int m = (wv + i * 14) * 16 + ln15;
            if (m > 440) m = 440;            // M-pad: valid row, discarded on write
            abase2[i] = ((m / 21) * 25 + (m % 21)) * SH1_STRIDE;
        }
        float bias[4];
        #pragma unroll
        for (int nt = 0; nt < 4; ++nt) {
            int o = nt * 16 + ln15;
            bias[nt] = (o < 60) ? c2b[o] : 0.f;
        }
        f32x4 acc2[2][4];
        #pragma unroll
        for (int i = 0; i < 2; ++i)
            #pragma unroll
            for (int nt = 0; nt < 4; ++nt)
                acc2[i][nt] = (f32x4){0.f, 0.f, 0.f, 0.f};

        const unsigned short* wb = w2frag + lane * 8;
        #pragma unroll
        for (int p = 0; p < 5; ++p) {
            #pragma unroll
            for (int q = 0; q < 5; ++q) {
                const int tap  = p * 5 + q;
                const int toff = (p * 25 + q) * SH1_STRIDE;
                bf16x8 b[4];
                #pragma unroll
                for (int nt = 0; nt < 4; ++nt)
                    b[nt] = *(const bf16x8*)(wb + (tap * 4 + nt) * 512);
                #pragma unroll
                for (int i = 0; i < 2; ++i) {
                    bf16x8 a = *(const bf16x8*)(sbuf + abase2[i] + toff + quad * 16);  // b128
                    #pragma unroll
                    for (int nt = 0; nt < 4; ++nt)
                        acc2[i][nt] = mfma_bf16(a, b[nt], acc2[i][nt]);
                }
            }
        }
        // writeback: relu -> sH2 [pixel][60ch bf16]
        #pragma unroll
        for (int i = 0; i < 2; ++i) {
            #pragma unroll
            for (int r = 0; r < 4; ++r) {
                int pix = (wv + i * 14) * 16 + quad * 4 + r;
                if (pix < 441) {
                    unsigned short* rowp = (unsigned short*)(sbuf + SH2_BASE + pix * SH2_STRIDE);
                    #pragma unroll
                    for (int nt = 0; nt < 4; ++nt) {
                        int o = nt * 16 + ln15;
                        if (o < 60)
                            rowp[o] = f2bf(fmaxf(acc2[i][nt][r] + bias[nt], 0.f));
                    }
                }
            }
        }
    }
    __syncthreads();

    // ---- S3: deconv2 as MFMA. M=625(->640, 40 mtiles), N=32 (24+8 pad),
    //      K=64 (60+4 B-zero), 25 taps. Wave wv: mtiles {wv, wv+16, wv+32<40} ----
    f32x4 acc3[3][2];
    {
        #pragma unroll
        for (int i = 0; i < 3; ++i) {
            acc3[i][0] = (f32x4){0.f, 0.f, 0.f, 0.f};
            acc3[i][1] = (f32x4){0.f, 0.f, 0.f, 0.f};
        }
        int uarr[3], varr[3], a120[3];
        bool mval[3];
        #pragma unroll
        for (int i = 0; i < 3; ++i) {
            int m = (wv + i * 16) * 16 + ln15;
            mval[i] = (m < 625);
            int mc = mval[i] ? m : 0;
            uarr[i] = mc / 25; varr[i] = mc % 25;
            a120[i] = (uarr[i] * 21 + varr[i]) * SH2_STRIDE;
        }
        const unsigned short* db = dw2frag + lane * 8;
        #pragma unroll
        for (int dy = 0; dy < 5; ++dy) {
            #pragma unroll
            for (int dx = 0; dx < 5; ++dx) {
                const int tap   = dy * 5 + dx;
                const int t2off = (dy * 21 + dx) * SH2_STRIDE;
                bf16x8 b00 = *(const bf16x8*)(db + tap * 2048);
                bf16x8 b01 = *(const bf16x8*)(db + tap * 2048 + 512);
                bf16x8 b10 = *(const bf16x8*)(db + tap * 2048 + 1024);
                bf16x8 b11 = *(const bf16x8*)(db + tap * 2048 + 1536);
                #pragma unroll
                for (int i = 0; i < 3; ++i) {
                    if (i == 2 && wv >= 8) continue;       // wave-uniform skip
                    int yv = uarr[i] - dy, xv = varr[i] - dx;
                    bool ok = mval[i] && ((unsigned)yv < 21u) && ((unsigned)xv < 21u);
                    int ra = ok ? (a120[i] - t2off) : ZROW_REL;  // zero row -> +0
                    const char* ap = sbuf + SH2_BASE + ra + quad * 16;
                    short4v lo0 = *(const short4v*)(ap);          // ds_read_b64
                    short4v hi0 = *(const short4v*)(ap + 8);
                    bf16x8 a0 = __builtin_shufflevector(lo0, hi0, 0, 1, 2, 3, 4, 5, 6, 7);
                    acc3[i][0] = mfma_bf16(a0, b00, acc3[i][0]);
                    acc3[i][1] = mfma_bf16(a0, b01, acc3[i][1]);
                    short4v lo1 = *(const short4v*)(ap + 64);
                    short4v hi1 = *(const short4v*)(ap + 72);
                    bf16x8 a1 = __builtin_shufflevector(lo1, hi1, 0, 1, 2, 3, 4, 5, 6, 7);
                    acc3[i][0] = mfma_bf16(a1, b10, acc3[i][0]);
                    acc3[i][1] = mfma_bf16(a1, b11, acc3[i][1]);
                }
            }
        }
    }
    __syncthreads();   // sH1 & sH2 fully dead from here

    // ---- S4a: h3 = elu(acc3 + d2b) -> bf16 [625][24ch] stride 48B;
    //           build sWc (bf16, c>=24 zero); zero sp ----
    const float lw0 = lin_w[2 * n], lw1 = lin_w[2 * n + 1];
    float* sp = (float*)(sbuf + SP_ACC);
    {
        const int c0 = ln15, c1 = 16 + ln15;
        const float db0 = d2b[c0];
        const float db1 = (c1 < 24) ? d2b[c1] : 0.f;
        #pragma unroll
        for (int i = 0; i < 3; ++i) {
            if (i == 2 && wv >= 8) continue;
            #pragma unroll
            for (int r = 0; r < 4; ++r) {
                int pix = (wv + i * 16) * 16 + quad * 4 + r;
                if (pix < 625) {
                    unsigned short* rowp = (unsigned short*)(sbuf + pix * SH1_STRIDE);
                    float hv = acc3[i][0][r] + db0;
                    rowp[c0] = f2bf(hv > 0.f ? hv : expm1f(hv));
                    if (c1 < 24) {
                        float hw = acc3[i][1][r] + db1;
                        rowp[c1] = f2bf(hw > 0.f ? hw : expm1f(hw));
                    }
                }
            }
        }
    }
    for (int k = t; k < 2048; k += 1024) {   // sWc: 64 r x 32 c, stride 64B
        int r = k >> 5, c = k & 31;
        float v = 0.f;
        if (c < 24)
            v = lw0 * dw1[(c * 2 + 0) * 64 + r] + lw1 * dw1[(c * 2 + 1) * 64 + r];
        ((unsigned short*)(sbuf + SWC_BASE))[r * 32 + c] = f2bf(v);
    }
    sp[t] = 0.f;
    __syncthreads();

    // ---- S4b: epilogue GEMM p[pix][r] = sum_c h3[pix][c]*wc[r][c] (K=32),
    //           scatter-add into sp via LDS atomics ----
    {
        bf16x8 wbv[4];
        #pragma unroll
        for (int nt = 0; nt < 4; ++nt)
            wbv[nt] = *(const bf16x8*)(sbuf + SWC_BASE + (nt * 16 + ln15) * 64 + quad * 16);
        #pragma unroll
        for (int i = 0; i < 3; ++i) {
            int mt = wv + i * 16;
            if (mt >= 40) continue;                 // wave-uniform
            int m = mt * 16 + ln15;
            if (m > 624) m = 624;
            bf16x8 a = *(const bf16x8*)(sbuf + m * SH1_STRIDE + quad * 16);  // b128
            #pragma unroll
            for (int nt = 0; nt < 4; ++nt) {
                f32x4 acc4 = (f32x4){0.f, 0.f, 0.f, 0.f};
                acc4 = mfma_bf16(a, wbv[nt], acc4);
                #pragma unroll
                for (int r = 0; r < 4; ++r) {
                    int pix = mt * 16 + quad * 4 + r;
                    if (pix < 625) {
                        int u = pix / 25, v = pix % 25;
                        int rv = nt * 16 + ln15;
                        atomicAdd(&sp[(u + (rv >> 3)) * 32 + v + (rv & 7)], acc4[r]);
                    }
                }
            }
        }
    }
    __syncthreads();

    // ---- S5: overlap-add into global recon ----
    const float obias = d1b[0] * (lw0 + lw1) + lin_b[n];
    {
        int yy = t >> 5, xx = t & 31;
        atomicAdd(&recon[(Y0 + yy) * W_ + (X0 + xx)], sp[t] + obias);
    }
}

// ---------------------------------------------------------------------------
// Prep (layouts unchanged from R4):
//  conv1:   i = (kc*2+nt)*512 + lane*8 + j -> n=nt*16+(lane&15), k=kc*32+(lane>>4)*8+j
//  conv2:   tap*2048 + nt*512 + lane*8 + j -> o=nt*16+ln15, c=quad*8+j (zeros o>=60, c>=24)
//  deconv2: tap*2048 + kc*1024 + nt*512 + lane*8 + j -> k=kc*32+quad*8+j, c=nt*16+ln15
//           (zeros k>=60, c>=24)
// ---------------------------------------------------------------------------
__global__ void prep_kernel(const float* __restrict__ c1w,
                            const float* __restrict__ c2w,
                            const float* __restrict__ d2w,
                            unsigned short* __restrict__ w1frag,
                            unsigned short* __restrict__ w2frag,
                            unsigned short* __restrict__ dw2frag)
{
    int i = blockIdx.x * blockDim.x + threadIdx.x;
    if (i < 51200) {
        int j = i & 7, lane = (i >> 3) & 63;
        int ln15 = lane & 15, quad = lane >> 4;
        if (i < 4096) {   // conv1
            int g = i >> 9;                   // = kc*2 + nt
            int kc = g >> 1, nt = g & 1;
            int nn = nt * 16 + ln15, k = kc * 32 + quad * 8 + j;
            w1frag[i] = f2bf((nn < 24) ? c1w[nn * 128 + k] : 0.f);
        }
        {   // conv2
            int nt = (i >> 9) & 3, tap = i >> 11;
            int o = nt * 16 + ln15, c = quad * 8 + j;
            float v = (o < 60 && c < 24) ? c2w[(o * 24 + c) * 25 + tap] : 0.f;
            w2frag[i] = f2bf(v);
        }
        {   // deconv2
            int nt = (i >> 9) & 1, kc = (i >> 10) & 1, tap = i >> 11;
            int k = kc * 32 + quad * 8 + j, c = nt * 16 + ln15;
            float v = (k < 60 && c < 24) ? d2w[(k * 24 + c) * 25 + tap] : 0.f;
            dw2frag[i] = f2bf(v);
        }
    }
}

__global__ void finalize_kernel(const float* __restrict__ x2,
                                const float* __restrict__ l1w,
                                float* __restrict__ out)
{
    int i = blockIdx.x * blockDim.x + threadIdx.x;
    if (i < H_ * W_) {
        float r = out[i];
        out[i] = x2[i] - r * l1w[0];
    }
}

extern "C" void kernel_launch(void* const* d_in, const int* in_sizes, int n_in,
                              void* d_out, int out_size, void* d_ws, size_t ws_size,
                              hipStream_t stream)
{
    const float* x1  = (const float*)d_in[0];
    const float* x2  = (const float*)d_in[1];
    const float* c1w = (const float*)d_in[2];
    const float* c1b = (const float*)d_in[3];
    const float* c2w = (const float*)d_in[4];
    const float* c2b = (const float*)d_in[5];
    const float* d2w = (const float*)d_in[6];
    const float* d2b = (const float*)d_in[7];
    const float* d1w = (const float*)d_in[8];
    const float* d1b = (const float*)d_in[9];
    const float* lw  = (const float*)d_in[10];
    const float* lb  = (const float*)d_in[11];
    const float* l1w = (const float*)d_in[12];

    float*          out     = (float*)d_out;
    unsigned short* w1frag  = (unsigned short*)d_ws;                      // 8192 B
    unsigned short* w2frag  = (unsigned short*)((char*)d_ws + 8192);      // 102400 B
    unsigned short* dw2frag = (unsigned short*)((char*)d_ws + 110592);    // 102400 B

    hipMemsetAsync(d_out, 0, (size_t)H_ * W_ * sizeof(float), stream);
    prep_kernel<<<100, 512, 0, stream>>>(c1w, c2w, d2w, w1frag, w2frag, dw2frag);
    fused_patch_kernel<<<NPATCH_, 1024, 0, stream>>>(x1, x2, c1b, c2b, d2b, d1b,
                                                     lw, lb, w1frag, w2frag, dw2frag,
                                                     d1w, out);
    finalize_kernel<<<(H_ * W_ + 255) / 256, 256, 0, stream>>>(x2, l1w, out);
}